// Round 9
// baseline (727.594 us; speedup 1.0000x reference)
//
#include <hip/hip_runtime.h>
#include <stdint.h>

// ---------------------------------------------------------------------------
// FakeNewsModel: 3-layer GraphSAGE (mean agg), N=50000, E=1.6M, width 64.
// Round 12: k_project v10 — MFMA. Eight rounds of counters showed the
// VALU-path ceiling (~22us pure issue in 93us kernel, MfmaUtil 0.0) for what
// is a bf16 GEMM. New BF path: block = 64 nodes, 4 waves; wave w = M-tile w
// (16 rows x 64 cols, 4 f32x4 accs). W permuted once/block into LDS
// B-fragment layout (56 frags x 1KB = 57344B). K-loop: 28 steps (24 content
// + 4 style): 16B/lane A-load direct from global (x read EXACTLY once, no
// staging), 2 contiguous ds_read_b128 B-frags, 2 mfma_f32_16x16x32_bf16;
// A pipelined 2-deep (~16KB in flight/CU > ~9KB BW-saturation). Epilogue
// adds bias. K-split + k_combine deleted (WRITE back to 12.5MB). fp32
// fallback = round-9 v8 body (not exercised by this bench). Everything else
// identical to round-11.
//   k_detect  -> flags[0]=floats-are-bf16?, flags[1]=ints-are-int64?
//   CSR build -> memset(cnt), k_pack, k_scan1/2/3, k_scatter2 x4
//   k_project -> x0 = concat(xc@Wp+bp, xs@Ws+bs)  (fp32 h-table)
//   k_layer x3 -> relu(mean-agg@Wl + bl + x@Wr); layer 3 fuses [64,2] head.
// ---------------------------------------------------------------------------

typedef __attribute__((ext_vector_type(8))) unsigned short u16x8;
typedef __attribute__((ext_vector_type(8))) short bf16x8;   // MFMA A/B frag
typedef __attribute__((ext_vector_type(4))) float f32x4;
typedef __attribute__((ext_vector_type(4))) unsigned int u32x4;
typedef __attribute__((ext_vector_type(2))) int i32x2;

static __device__ __forceinline__ float bf2f(unsigned short u) {
  union { unsigned int i; float f; } v;
  v.i = ((unsigned int)u) << 16;
  return v.f;
}

static __device__ __forceinline__ unsigned short f2bf(float f) {
  union { float f; unsigned int i; } v;
  v.f = f;
  unsigned int u = v.i;
  unsigned int r = (u + 0x7FFFu + ((u >> 16) & 1u)) >> 16;  // RNE
  return (unsigned short)r;
}

template <bool BF>
static __device__ __forceinline__ float ldf(const void* p, long long i) {
  if (BF) return bf2f(((const unsigned short*)p)[i]);
  return ((const float*)p)[i];
}

static __device__ __forceinline__ int clampN(int v, int N) {
  return v < 0 ? 0 : (v >= N ? N - 1 : v);
}

// ---------------- dtype detection ----------------
__global__ void k_detect(const void* Wp, const int* ei, int* flags) {
  if (threadIdx.x == 0 && blockIdx.x == 0) {
    const unsigned short* w = (const unsigned short*)Wp;
    int bf = 1;
    for (int i = 0; i < 64; ++i) {
      float v = fabsf(bf2f(w[i]));
      if (!(v < 1.0f)) bf = 0;  // catches NaN too
    }
    flags[0] = bf;
    int i64 = 1;
    for (int i = 0; i < 32; ++i)
      if (ei[2 * i + 1] != 0) i64 = 0;
    flags[1] = i64;
  }
}

static __device__ __forceinline__ int edge_src(const int* ei, int e, int E,
                                               int i64) {
  return i64 ? ei[2 * (long long)e] : ei[e];
}
static __device__ __forceinline__ int edge_dst(const int* ei, int e, int E,
                                               int i64) {
  return i64 ? ei[2 * ((long long)E + e)] : ei[(long long)E + e];
}

// ---------------- CSR build ----------------

// pack (src,dst) into a compact coalesced stream + count degrees.
__global__ __launch_bounds__(256) void k_pack(const int* __restrict__ ei, int E,
                                              int N, int* __restrict__ cnt,
                                              i32x2* __restrict__ pairs,
                                              const int* __restrict__ flags) {
  int e = blockIdx.x * 256 + threadIdx.x;
  if (e < E) {
    int i64 = flags[1];
    int s = clampN(edge_src(ei, e, E, i64), N);
    int d = clampN(edge_dst(ei, e, E, i64), N);
    i32x2 p;
    p[0] = s;
    p[1] = d;
    pairs[e] = p;
    atomicAdd(&cnt[d], 1);
  }
}

__global__ __launch_bounds__(256) void k_scan1(const int* __restrict__ cnt,
                                               int* __restrict__ rowptr,
                                               int* __restrict__ bsum, int N) {
  __shared__ int sh[256];
  int t = threadIdx.x;
  int base = blockIdx.x * 1024 + t * 4;
  int v0 = 0, v1 = 0, v2 = 0, v3 = 0;
  if (base + 0 < N) v0 = cnt[base + 0];
  if (base + 1 < N) v1 = cnt[base + 1];
  if (base + 2 < N) v2 = cnt[base + 2];
  if (base + 3 < N) v3 = cnt[base + 3];
  int s = v0 + v1 + v2 + v3;
  sh[t] = s;
  __syncthreads();
  int acc = s;
  for (int off = 1; off < 256; off <<= 1) {
    int x = 0;
    if (t >= off) x = sh[t - off];
    __syncthreads();
    acc += x;
    sh[t] = acc;
    __syncthreads();
  }
  int run = acc - s;
  if (base + 0 < N) rowptr[base + 0] = run;
  run += v0;
  if (base + 1 < N) rowptr[base + 1] = run;
  run += v1;
  if (base + 2 < N) rowptr[base + 2] = run;
  run += v2;
  if (base + 3 < N) rowptr[base + 3] = run;
  run += v3;
  if (t == 255) bsum[blockIdx.x] = acc;
}

__global__ void k_scan2(int* __restrict__ bsum, int nb,
                        int* __restrict__ rowptr, int N) {
  if (threadIdx.x == 0 && blockIdx.x == 0) {
    int run = 0;
    for (int i = 0; i < nb; ++i) {
      int v = bsum[i];
      bsum[i] = run;
      run += v;
    }
    rowptr[N] = run;
  }
}

__global__ __launch_bounds__(256) void k_scan3(int* __restrict__ rowptr,
                                               int* __restrict__ cursor,
                                               const int* __restrict__ bsum,
                                               int N) {
  int i = blockIdx.x * 256 + threadIdx.x;
  if (i < N) {
    int v = rowptr[i] + bsum[i >> 10];
    rowptr[i] = v;
    cursor[i] = v;
  }
}

// one dst-range pass: only edges with dst in [lo,hi) write. The pass's
// colbuf write window (~E/4*4B ~ 1.6MB) stays L2-resident -> line packing.
__global__ __launch_bounds__(256) void k_scatter2(
    const i32x2* __restrict__ pairs, int E, int lo, int hi,
    int* __restrict__ cursor, int* __restrict__ colbuf) {
  int e = blockIdx.x * 256 + threadIdx.x;
  if (e < E) {
    i32x2 p2 = pairs[e];
    int d = p2[1];
    if (d >= lo && d < hi) {
      int p = atomicAdd(&cursor[d], 1);
      if (p >= 0 && p < E) colbuf[p] = p2[0];
    }
  }
}

// ---------------- projection v10: MFMA (bf16 path) --------------------------
// Block = 256 threads = 4 waves = 64 nodes. Wave w = M-tile w (16 rows).
// B = block-diagonal [896 x 64]: rows 0..767 -> Wp (cols 0..31), rows
// 768..895 -> Ws (cols 32..63). 28 k-steps of 32: s<24 content (n-tiles 0,1
// -> acc0/1), s>=24 style (n-tiles 2,3 -> acc2/3).
// B-fragments staged once per block into LDS: frag f (56 total) holds lane l:
// B[k=(l>>4)*8+j][col=f's n-tile*16 + (l&15)], j=0..7, contiguous 16B/lane.
//   content: f = s*2 + nt (nt 0,1);  style: f = 48 + s*2 + nt' (nt' 0,1).
// A-frag: lane l loads x[row=node0+16w+(l&15)][k0+(l>>4)*8 ..+8] (16B global,
// x read exactly once, no LDS). 2-deep A pipeline. C/D: col=lane&15,
// row=(lane>>4)*4+reg [m89]. Epilogue adds bias, guarded store.
static __device__ void project_mfma(const void* __restrict__ xc,
                                    const void* __restrict__ xs,
                                    const void* __restrict__ Wp,
                                    const void* __restrict__ bp,
                                    const void* __restrict__ Ws,
                                    const void* __restrict__ bs,
                                    float* __restrict__ h0, int N,
                                    float* __restrict__ lds) {
  unsigned short* fb = (unsigned short*)lds;  // 56 frags x 512 u16
  int tid = (int)threadIdx.x;
  int w = __builtin_amdgcn_readfirstlane(tid >> 6);  // M-tile 0..3
  int l = tid & 63;
  int node0 = (int)blockIdx.x * 64;

  // ---- stage B-fragments: 3584 chunks of 8 elems; 14 per thread ----
  const unsigned short* wp16 = (const unsigned short*)Wp;
  const unsigned short* ws16 = (const unsigned short*)Ws;
#pragma unroll
  for (int i = 0; i < 14; ++i) {
    int ci = tid + 256 * i;        // 0..3583
    int e0 = ci * 8;               // elem in concat(Wp[768*32], Ws[128*32])
    int isC = e0 < 24576;
    int eb = isC ? e0 : (e0 - 24576);
    int r = eb >> 5;               // k-row within its matrix
    int c0 = eb & 31;              // 0,8,16,24
    int s_ = r >> 5;               // k-step
    int g = (r >> 3) & 3;          // lane group (k>>3 within step)
    int j = r & 7;                 // elem slot
    int f = isC ? (s_ * 2 + (c0 >> 4)) : (48 + s_ * 2 + (c0 >> 4));
    u16x8 v = *(const u16x8*)((isC ? wp16 : ws16) + eb);
    unsigned short* d = fb + f * 512 + ((g << 4) + (c0 & 15)) * 8 + j;
#pragma unroll
    for (int m = 0; m < 8; ++m) d[m * 8] = v[m];
  }
  __syncthreads();

  // ---- K loop: 28 steps, A 2-deep pipeline ----
  int arow = node0 + 16 * w + (l & 15);
  int arowc = arow < N ? arow : (N - 1);
  int kg = (l >> 4) * 8;  // k sub-offset within step
  const unsigned short* xcl = (const unsigned short*)xc + (long long)arowc * 768;
  const unsigned short* xsl = (const unsigned short*)xs + (long long)arowc * 128;

  auto loadA = [&](int s) -> bf16x8 {
    if (s < 24) return *(const bf16x8*)(xcl + s * 32 + kg);
    return *(const bf16x8*)(xsl + (s - 24) * 32 + kg);
  };

  f32x4 ac0 = {0.f, 0.f, 0.f, 0.f};
  f32x4 ac1 = {0.f, 0.f, 0.f, 0.f};
  f32x4 ac2 = {0.f, 0.f, 0.f, 0.f};
  f32x4 ac3 = {0.f, 0.f, 0.f, 0.f};

  bf16x8 a0 = loadA(0);
  bf16x8 a1 = loadA(1);
#pragma unroll 1
  for (int s = 0; s < 28; ++s) {
    bf16x8 acur = a0;
    a0 = a1;
    if (s + 2 < 28) a1 = loadA(s + 2);
    if (s < 24) {
      bf16x8 b0 = *(const bf16x8*)(fb + (s * 2 + 0) * 512 + l * 8);
      bf16x8 b1 = *(const bf16x8*)(fb + (s * 2 + 1) * 512 + l * 8);
      ac0 = __builtin_amdgcn_mfma_f32_16x16x32_bf16(acur, b0, ac0, 0, 0, 0);
      ac1 = __builtin_amdgcn_mfma_f32_16x16x32_bf16(acur, b1, ac1, 0, 0, 0);
    } else {
      int sb = s - 24;
      bf16x8 b2 = *(const bf16x8*)(fb + (48 + sb * 2 + 0) * 512 + l * 8);
      bf16x8 b3 = *(const bf16x8*)(fb + (48 + sb * 2 + 1) * 512 + l * 8);
      ac2 = __builtin_amdgcn_mfma_f32_16x16x32_bf16(acur, b2, ac2, 0, 0, 0);
      ac3 = __builtin_amdgcn_mfma_f32_16x16x32_bf16(acur, b3, ac3, 0, 0, 0);
    }
  }

  // ---- epilogue: C[row=(l>>4)*4+r][col=nt*16+(l&15)] + bias ----
  int colb = l & 15;
  int rbase = (l >> 4) * 4;
#pragma unroll
  for (int r = 0; r < 4; ++r) {
    int nodeg = node0 + 16 * w + rbase + r;
    if (nodeg < N) {
      float* orow = h0 + (long long)nodeg * 64;
      orow[0 + colb] = ac0[r] + bf2f(((const unsigned short*)bp)[0 + colb]);
      orow[16 + colb] = ac1[r] + bf2f(((const unsigned short*)bp)[16 + colb]);
      orow[32 + colb] = ac2[r] + bf2f(((const unsigned short*)bs)[0 + colb]);
      orow[48 + colb] = ac3[r] + bf2f(((const unsigned short*)bs)[16 + colb]);
    }
  }
}

// ---------------- projection fallback (fp32, round-9 v8 body) ---------------
static __device__ void project_f32(const void* __restrict__ xc,
                                   const void* __restrict__ xs,
                                   const void* __restrict__ Wp,
                                   const void* __restrict__ bp,
                                   const void* __restrict__ Ws,
                                   const void* __restrict__ bs,
                                   float* __restrict__ h0, int N,
                                   float* __restrict__ lds) {
  float* xt = lds;                       // [2][64][68] f32
  float* wtf = lds + 2 * 64 * 68;        // [2][64][32] f32

  int tid = (int)threadIdx.x;
  int w = __builtin_amdgcn_readfirstlane(tid >> 6);
  int lane = tid & 63;
  int node = (int)blockIdx.x * 64 + lane;

  int sn = tid >> 2;
  int sj = tid & 3;
  int gsn = (int)blockIdx.x * 64 + sn;
  int gsnc = gsn < N ? gsn : (N - 1);

  float c[8], s[8];
#pragma unroll
  for (int r = 0; r < 8; ++r) {
    c[r] = 0.f;
    s[r] = 0.f;
  }

  f32x4 pf0 = {}, pf1 = {}, pf2 = {}, pf3 = {};
  f32x4 wf0 = {}, wf1 = {};

  auto stage_load = [&](int t) {
    long long idx;
    const void* src;
    if (t < 12) {
      src = xc;
      idx = (long long)gsnc * 768 + t * 64 + 16 * sj;
    } else {
      src = xs;
      idx = (long long)gsnc * 128 + (t - 12) * 64 + 16 * sj;
    }
    const float* p = (const float*)src + idx;
    pf0 = *(const f32x4*)(p + 0);
    pf1 = *(const f32x4*)(p + 4);
    pf2 = *(const f32x4*)(p + 8);
    pf3 = *(const f32x4*)(p + 12);
    int rowg = (t < 12) ? (t * 64 + sn) : ((t - 12) * 64 + sn);
    const float* wp = (const float*)((t < 12) ? Wp : Ws) +
                      (long long)rowg * 32 + 8 * sj;
    wf0 = *(const f32x4*)wp;
    wf1 = *(const f32x4*)(wp + 4);
  };

  auto stage_write = [&](int t) {
    float* row = xt + (t & 1) * (64 * 68) + sn * 68 + 16 * sj;
    *(f32x4*)(row + 0) = pf0;
    *(f32x4*)(row + 4) = pf1;
    *(f32x4*)(row + 8) = pf2;
    *(f32x4*)(row + 12) = pf3;
    float* wrow = wtf + (t & 1) * (64 * 32) + sn * 32 + 8 * sj;
    *(f32x4*)wrow = wf0;
    *(f32x4*)(wrow + 4) = wf1;
  };

  stage_load(0);
  stage_write(0);
  __syncthreads();

#pragma unroll 1
  for (int t = 0; t < 14; ++t) {
    if (t + 1 < 14) stage_load(t + 1);
    const float* xrow = xt + (t & 1) * (64 * 68) + lane * 68;
    const float* wbase = wtf + (t & 1) * (64 * 32) + 8 * w;
    float* acc = (t < 12) ? c : s;
#pragma unroll 2
    for (int k0 = 0; k0 < 64; k0 += 4) {
      f32x4 x4 = *(const f32x4*)(xrow + k0);
#pragma unroll
      for (int kk = 0; kk < 4; ++kk) {
        const float* wr = wbase + (k0 + kk) * 32;
        f32x4 wa = *(const f32x4*)wr;
        f32x4 wb = *(const f32x4*)(wr + 4);
#pragma unroll
        for (int r = 0; r < 4; ++r) {
          acc[r] += x4[kk] * wa[r];
          acc[4 + r] += x4[kk] * wb[r];
        }
      }
    }
    if (t + 1 < 14) stage_write(t + 1);
    __syncthreads();
  }

  if (node < N) {
    float* orow = h0 + (long long)node * 64;
    f32x4 v;
#pragma unroll
    for (int r = 0; r < 4; ++r) v[r] = c[r] + ((const float*)bp)[8 * w + r];
    *(f32x4*)(orow + 8 * w) = v;
#pragma unroll
    for (int r = 0; r < 4; ++r)
      v[r] = c[4 + r] + ((const float*)bp)[8 * w + 4 + r];
    *(f32x4*)(orow + 8 * w + 4) = v;
#pragma unroll
    for (int r = 0; r < 4; ++r) v[r] = s[r] + ((const float*)bs)[8 * w + r];
    *(f32x4*)(orow + 32 + 8 * w) = v;
#pragma unroll
    for (int r = 0; r < 4; ++r)
      v[r] = s[4 + r] + ((const float*)bs)[8 * w + 4 + r];
    *(f32x4*)(orow + 32 + 8 * w + 4) = v;
  }
}

__global__ __launch_bounds__(256) void k_project(
    const void* __restrict__ xc, const void* __restrict__ xs,
    const void* __restrict__ Wp, const void* __restrict__ bp,
    const void* __restrict__ Ws, const void* __restrict__ bs,
    float* __restrict__ h0, int N, const int* __restrict__ flags) {
  // union: MFMA B-frags 57344 B  |  fp32 path xt+wt 51200 B
  __shared__ float lds[14336];  // 57344 B
  if (flags[0])
    project_mfma(xc, xs, Wp, bp, Ws, bs, h0, N, lds);
  else
    project_f32(xc, xs, Wp, bp, Ws, bs, h0, N, lds);
}

// ---------------- SAGE layer ----------------
template <bool BF>
static __device__ void layer_body(const float* __restrict__ hin,
                                  const int* __restrict__ rowptr,
                                  const int* __restrict__ colbuf,
                                  const void* Wl, const void* bl,
                                  const void* Wr, float* __restrict__ hout,
                                  int N, int last, const void* Wo,
                                  const void* bo, void* outp) {
  int node = (int)((blockIdx.x * blockDim.x + threadIdx.x) >> 6);
  int lane = (int)(threadIdx.x & 63);
  if (node >= N) return;
  int rs = rowptr[node], re = rowptr[node + 1];
  float xself = hin[(long long)node * 64 + lane];
  float agg0 = 0.f, agg1 = 0.f, agg2 = 0.f, agg3 = 0.f;
  float agg4 = 0.f, agg5 = 0.f, agg6 = 0.f, agg7 = 0.f;
  for (int cb = rs; cb < re; cb += 64) {
    int sidx = 0;
    if (cb + lane < re) sidx = clampN(colbuf[cb + lane], N);
    int c = re - cb;
    if (c > 64) c = 64;
    int t = 0;
    for (; t + 16 <= c; t += 16) {
      int s0 = __builtin_amdgcn_readlane(sidx, t + 0);
      int s1 = __builtin_amdgcn_readlane(sidx, t + 1);
      int s2 = __builtin_amdgcn_readlane(sidx, t + 2);
      int s3 = __builtin_amdgcn_readlane(sidx, t + 3);
      int s4 = __builtin_amdgcn_readlane(sidx, t + 4);
      int s5 = __builtin_amdgcn_readlane(sidx, t + 5);
      int s6 = __builtin_amdgcn_readlane(sidx, t + 6);
      int s7 = __builtin_amdgcn_readlane(sidx, t + 7);
      int s8 = __builtin_amdgcn_readlane(sidx, t + 8);
      int s9 = __builtin_amdgcn_readlane(sidx, t + 9);
      int sa = __builtin_amdgcn_readlane(sidx, t + 10);
      int sb = __builtin_amdgcn_readlane(sidx, t + 11);
      int sc = __builtin_amdgcn_readlane(sidx, t + 12);
      int sd = __builtin_amdgcn_readlane(sidx, t + 13);
      int se = __builtin_amdgcn_readlane(sidx, t + 14);
      int sf = __builtin_amdgcn_readlane(sidx, t + 15);
      float v0 = hin[(long long)s0 * 64 + lane];
      float v1 = hin[(long long)s1 * 64 + lane];
      float v2 = hin[(long long)s2 * 64 + lane];
      float v3 = hin[(long long)s3 * 64 + lane];
      float v4 = hin[(long long)s4 * 64 + lane];
      float v5 = hin[(long long)s5 * 64 + lane];
      float v6 = hin[(long long)s6 * 64 + lane];
      float v7 = hin[(long long)s7 * 64 + lane];
      float v8 = hin[(long long)s8 * 64 + lane];
      float v9 = hin[(long long)s9 * 64 + lane];
      float va = hin[(long long)sa * 64 + lane];
      float vb = hin[(long long)sb * 64 + lane];
      float vc = hin[(long long)sc * 64 + lane];
      float vd = hin[(long long)sd * 64 + lane];
      float ve = hin[(long long)se * 64 + lane];
      float vf = hin[(long long)sf * 64 + lane];
      agg0 += v0 + v8;
      agg1 += v1 + v9;
      agg2 += v2 + va;
      agg3 += v3 + vb;
      agg4 += v4 + vc;
      agg5 += v5 + vd;
      agg6 += v6 + ve;
      agg7 += v7 + vf;
    }
    for (; t + 8 <= c; t += 8) {
      int s0 = __builtin_amdgcn_readlane(sidx, t + 0);
      int s1 = __builtin_amdgcn_readlane(sidx, t + 1);
      int s2 = __builtin_amdgcn_readlane(sidx, t + 2);
      int s3 = __builtin_amdgcn_readlane(sidx, t + 3);
      int s4 = __builtin_amdgcn_readlane(sidx, t + 4);
      int s5 = __builtin_amdgcn_readlane(sidx, t + 5);
      int s6 = __builtin_amdgcn_readlane(sidx, t + 6);
      int s7 = __builtin_amdgcn_readlane(sidx, t + 7);
      float v0 = hin[(long long)s0 * 64 + lane];
      float v1 = hin[(long long)s1 * 64 + lane];
      float v2 = hin[(long long)s2 * 64 + lane];
      float v3 = hin[(long long)s3 * 64 + lane];
      float v4 = hin[(long long)s4 * 64 + lane];
      float v5 = hin[(long long)s5 * 64 + lane];
      float v6 = hin[(long long)s6 * 64 + lane];
      float v7 = hin[(long long)s7 * 64 + lane];
      agg0 += v0;
      agg1 += v1;
      agg2 += v2;
      agg3 += v3;
      agg4 += v4;
      agg5 += v5;
      agg6 += v6;
      agg7 += v7;
    }
    for (; t < c; ++t) {
      int s = __builtin_amdgcn_readlane(sidx, t);
      agg0 += hin[(long long)s * 64 + lane];
    }
  }
  float agg = ((agg0 + agg1) + (agg2 + agg3)) + ((agg4 + agg5) + (agg6 + agg7));
  int deg = re - rs;
  if (deg > 0) agg *= (1.f / (float)deg);

  float o = ldf<BF>(bl, lane);
#pragma unroll 8
  for (int d = 0; d < 64; ++d) {
    float ad = __uint_as_float(
        __builtin_amdgcn_readlane(__float_as_uint(agg), d));
    float xd = __uint_as_float(
        __builtin_amdgcn_readlane(__float_as_uint(xself), d));
    o += ad * ldf<BF>(Wl, d * 64 + lane);
    o += xd * ldf<BF>(Wr, d * 64 + lane);
  }
  o = fmaxf(o, 0.f);

  if (!last) {
    hout[(long long)node * 64 + lane] = o;
  } else {
    float c0 = o * ldf<BF>(Wo, lane * 2 + 0);
    float c1 = o * ldf<BF>(Wo, lane * 2 + 1);
    for (int off = 32; off > 0; off >>= 1) {
      c0 += __shfl_xor(c0, off, 64);
      c1 += __shfl_xor(c1, off, 64);
    }
    if (lane == 0) {
      float r0 = c0 + ldf<BF>(bo, 0);
      float r1 = c1 + ldf<BF>(bo, 1);
      if (BF) {
        unsigned short* o16 = (unsigned short*)outp;
        o16[(long long)node * 2 + 0] = f2bf(r0);
        o16[(long long)node * 2 + 1] = f2bf(r1);
      } else {
        float* o32 = (float*)outp;
        o32[(long long)node * 2 + 0] = r0;
        o32[(long long)node * 2 + 1] = r1;
      }
    }
  }
}

__global__ __launch_bounds__(256) void k_layer(
    const float* hin, const int* rowptr, const int* colbuf, const void* Wl,
    const void* bl, const void* Wr, float* hout, int N, int last,
    const void* Wo, const void* bo, void* outp, const int* __restrict__ flags) {
  if (flags[0])
    layer_body<true>(hin, rowptr, colbuf, Wl, bl, Wr, hout, N, last, Wo, bo,
                     outp);
  else
    layer_body<false>(hin, rowptr, colbuf, Wl, bl, Wr, hout, N, last, Wo, bo,
                      outp);
}

// ---------------- host ----------------

extern "C" void kernel_launch(void* const* d_in, const int* in_sizes, int n_in,
                              void* d_out, int out_size, void* d_ws,
                              size_t ws_size, hipStream_t stream) {
  const void* xc = d_in[0];
  const void* xs = d_in[1];
  const int* ei = (const int*)d_in[2];
  const void* Wp = d_in[4];
  const void* bp = d_in[5];
  const void* Ws = d_in[6];
  const void* bs = d_in[7];
  const void* Wl1 = d_in[8];
  const void* bl1 = d_in[9];
  const void* Wr1 = d_in[10];
  const void* Wl2 = d_in[11];
  const void* bl2 = d_in[12];
  const void* Wr2 = d_in[13];
  const void* Wl3 = d_in[14];
  const void* bl3 = d_in[15];
  const void* Wr3 = d_in[16];
  const void* Wo = d_in[17];
  const void* bo = d_in[18];

  int N = out_size / 2;   // output is [N, 2]
  int E = in_sizes[3];    // edge_type has E elements

  char* ws = (char*)d_ws;
  size_t off = 0;
  auto alloc = [&](size_t bytes) {
    char* p = ws + off;
    off += (bytes + 255) & ~(size_t)255;
    return p;
  };
  int* colbuf = (int*)alloc((size_t)E * 4);
  int* cnt = (int*)alloc((size_t)N * 4);
  int* rowptr = (int*)alloc((size_t)(N + 1) * 4);
  int* cursor = (int*)alloc((size_t)N * 4);
  int* bsum = (int*)alloc(4096);
  int* flags = (int*)alloc(256);
  float* h0 = (float*)alloc((size_t)N * 64 * 4);
  float* h1 = (float*)alloc((size_t)N * 64 * 4);
  (void)ws_size;
  (void)n_in;

  // pairs (E * 8B) aliases h0 (N*64*4B = 12.8MB >= E*8B = 12.8MB):
  // written by k_pack, consumed by the scatter passes, then h0 is
  // overwritten by k_project (stream-ordered, safe).
  i32x2* pairs = (i32x2*)h0;

  k_detect<<<1, 64, 0, stream>>>(Wp, ei, flags);

  hipMemsetAsync(cnt, 0, (size_t)N * 4, stream);
  int eb = (E + 255) / 256;
  k_pack<<<eb, 256, 0, stream>>>(ei, E, N, cnt, pairs, flags);
  int sb = (N + 1023) / 1024;
  k_scan1<<<sb, 256, 0, stream>>>(cnt, rowptr, bsum, N);
  k_scan2<<<1, 64, 0, stream>>>(bsum, sb, rowptr, N);
  k_scan3<<<(N + 255) / 256, 256, 0, stream>>>(rowptr, cursor, bsum, N);

  const int NPASS = 4;
  int chunk = (N + NPASS - 1) / NPASS;
  for (int r = 0; r < NPASS; ++r) {
    int lo = r * chunk;
    int hi = lo + chunk < N ? lo + chunk : N;
    k_scatter2<<<eb, 256, 0, stream>>>(pairs, E, lo, hi, cursor, colbuf);
  }

  int pb = (N + 63) / 64;  // 64 nodes per 256-thread block (4 waves)
  k_project<<<pb, 256, 0, stream>>>(xc, xs, Wp, bp, Ws, bs, h0, N, flags);

  int nb4 = (N + 3) / 4;  // 4 waves (nodes) per 256-thread block
  k_layer<<<nb4, 256, 0, stream>>>(h0, rowptr, colbuf, Wl1, bl1, Wr1, h1, N, 0,
                                   nullptr, nullptr, nullptr, flags);
  k_layer<<<nb4, 256, 0, stream>>>(h1, rowptr, colbuf, Wl2, bl2, Wr2, h0, N, 0,
                                   nullptr, nullptr, nullptr, flags);
  k_layer<<<nb4, 256, 0, stream>>>(h0, rowptr, colbuf, Wl3, bl3, Wr3, h1, N, 1,
                                   Wo, bo, d_out, flags);
}